// Round 3
// baseline (446.964 us; speedup 1.0000x reference)
//
#include <hip/hip_runtime.h>
#include <cstdint>
#include <cstddef>

// B=32, N=2048, L=128, D=1024, V=32000
#define BATCH 32
#define NROW  2048
#define LTOK  128
#define DDIM  1024
#define BM    64            // rows per block
#define KC    (DDIM / 8)    // 128 k-chunks of 8

typedef short s8v __attribute__((ext_vector_type(8)));
typedef float f4v __attribute__((ext_vector_type(4)));

// Truncation-pack two fp32 -> packed bf16 pair in ONE v_perm_b32.
__device__ __forceinline__ uint32_t pk2(float lo, float hi) {
    return __builtin_amdgcn_perm(__float_as_uint(hi), __float_as_uint(lo), 0x07060302u);
}

// ---------- Pre-pass: gather + convert Y into [b][kc][t][8] bf16, compute y2 ----------
__global__ __launch_bounds__(256)
void prep_y(const int*   __restrict__ tok,
            const float* __restrict__ E,
            uint32_t*    __restrict__ Ypk,   // [B][KC][LTOK][8] bf16 as uints
            float*       __restrict__ y2)    // [B][LTOK]
{
    const int t = blockIdx.x, b = blockIdx.y, tid = threadIdx.x;
    const int tr = tok[b * LTOK + t];
    const float4 v = ((const float4*)(E + (size_t)tr * DDIM))[tid];
    float s = v.x*v.x + v.y*v.y + v.z*v.z + v.w*v.w;
    const int kc = tid >> 1;
    uint2 p; p.x = pk2(v.x, v.y); p.y = pk2(v.z, v.w);
    *(uint2*)(Ypk + (((size_t)(b * KC + kc) * LTOK + t) << 2) + ((tid & 1) << 1)) = p;
#pragma unroll
    for (int o = 1; o < 64; o <<= 1) s += __shfl_xor(s, o);
    __shared__ float ws4[4];
    if ((tid & 63) == 0) ws4[tid >> 6] = s;
    __syncthreads();
    if (tid == 0) y2[b * LTOK + t] = ws4[0] + ws4[1] + ws4[2] + ws4[3];
}

// ---------- Main: barrier-free streaming MFMA (no LDS in the K-loop) ----------
__global__ __launch_bounds__(256, 4)
void cdist_min_mean_kernel(const float* __restrict__ X,     // [B,N,D] fp32
                           const short* __restrict__ Ypk,   // [B][KC][LTOK][8] bf16
                           const float* __restrict__ y2g,   // [B,LTOK]
                           float* __restrict__ out)
{
    __shared__ float x2s[BM];
    __shared__ float rowmin[BM * 2];
    __shared__ float wsum[4];

    const int tid  = threadIdx.x;
    const int lane = tid & 63;
    const int wid  = tid >> 6;
    const int l15  = lane & 15;
    const int quad = lane >> 4;
    const int wrow = wid >> 1;   // 0..1 : which 32-row half
    const int wcol = wid & 1;    // 0..1 : which 64-token half

    // XCD swizzle: pin each batch's Y tile to one XCD's L2 (heuristic: xcd = id%8)
    const int L   = blockIdx.x;          // 0..1023
    const int xcd = L & 7;
    const int s   = L >> 3;              // 0..127
    const int b   = (xcd << 2) | (s >> 5);   // 4 batches per XCD
    const int rowBase = (s & 31) * BM;

    // A-operand row pointers (fragment-direct, fp32): mi = 0..1
    const float* xp[2];
#pragma unroll
    for (int mi = 0; mi < 2; ++mi) {
        int row = rowBase + wrow * 32 + mi * 16 + l15;
        xp[mi] = X + ((size_t)b * NROW + row) * DDIM + quad * 8;
    }
    // B-operand pointers (bf16, pre-transposed; 16B per fragment): ni = 0..3
    const s8v* ypp[4];
#pragma unroll
    for (int ni = 0; ni < 4; ++ni) {
        int tcol = wcol * 64 + ni * 16 + l15;
        ypp[ni] = (const s8v*)Ypk + ((size_t)(b * KC + quad) * LTOK + tcol);
    }

    f4v acc[2][4];
#pragma unroll
    for (int mi = 0; mi < 2; ++mi)
#pragma unroll
        for (int ni = 0; ni < 4; ++ni)
            acc[mi][ni] = (f4v){0.f, 0.f, 0.f, 0.f};

    float xs2[2] = {0.f, 0.f};

#pragma unroll 2
    for (int k0 = 0; k0 < DDIM; k0 += 32) {
        float4 xa[2], xb[2];
#pragma unroll
        for (int mi = 0; mi < 2; ++mi) {
            xa[mi] = *(const float4*)(xp[mi] + k0);
            xb[mi] = *(const float4*)(xp[mi] + k0 + 4);
        }
        s8v bfr[4];
        const int yoff = (k0 >> 3) * LTOK;   // k-chunk plane offset in s8v units
#pragma unroll
        for (int ni = 0; ni < 4; ++ni)
            bfr[ni] = ypp[ni][yoff];

        s8v afr[2];
#pragma unroll
        for (int mi = 0; mi < 2; ++mi) {
            const float4 a = xa[mi], c = xb[mi];
            if (wcol == 0)   // wave-uniform; wcol=1 waves skip redundant sumsq
                xs2[mi] += a.x*a.x + a.y*a.y + a.z*a.z + a.w*a.w
                         + c.x*c.x + c.y*c.y + c.z*c.z + c.w*c.w;
            uint4 p;
            p.x = pk2(a.x, a.y); p.y = pk2(a.z, a.w);
            p.z = pk2(c.x, c.y); p.w = pk2(c.z, c.w);
            afr[mi] = *(s8v*)&p;
        }
#pragma unroll
        for (int mi = 0; mi < 2; ++mi)
#pragma unroll
            for (int ni = 0; ni < 4; ++ni)
                acc[mi][ni] = __builtin_amdgcn_mfma_f32_16x16x32_bf16(
                    afr[mi], bfr[ni], acc[mi][ni], 0, 0, 0);
    }

    // x2: each lane holds its quad's k-chunks; reduce across quads (xor 16, 32)
#pragma unroll
    for (int mi = 0; mi < 2; ++mi) {
        float v = xs2[mi];
        v += __shfl_xor(v, 16);
        v += __shfl_xor(v, 32);
        if (wcol == 0 && quad == 0) x2s[wrow * 32 + mi * 16 + l15] = v;
    }

    // Row-min of (y2[col] - 2*S).  C/D layout: col = lane&15, row = quad*4 + j.
    float y2r[4];
#pragma unroll
    for (int ni = 0; ni < 4; ++ni)
        y2r[ni] = y2g[b * LTOK + wcol * 64 + ni * 16 + l15];

#pragma unroll
    for (int mi = 0; mi < 2; ++mi) {
#pragma unroll
        for (int j = 0; j < 4; ++j) {
            float m = y2r[0] - 2.f * acc[mi][0][j];
            m = fminf(m, y2r[1] - 2.f * acc[mi][1][j]);
            m = fminf(m, y2r[2] - 2.f * acc[mi][2][j]);
            m = fminf(m, y2r[3] - 2.f * acc[mi][3][j]);
            m = fminf(m, __shfl_xor(m, 1));
            m = fminf(m, __shfl_xor(m, 2));
            m = fminf(m, __shfl_xor(m, 4));
            m = fminf(m, __shfl_xor(m, 8));
            if (l15 == 0)
                rowmin[(wrow * 32 + mi * 16 + quad * 4 + j) * 2 + wcol] = m;
        }
    }
    __syncthreads();

    float part = 0.f;
    if (tid < BM) {
        float m = fminf(rowmin[tid * 2], rowmin[tid * 2 + 1]);
        part = sqrtf(fmaxf(x2s[tid] + m, 0.f));
    }
#pragma unroll
    for (int o = 1; o < 64; o <<= 1) part += __shfl_xor(part, o);
    if (lane == 0) wsum[wid] = part;
    __syncthreads();
    if (tid == 0) {
        float tot = (wsum[0] + wsum[1] + wsum[2] + wsum[3])
                  * (1.0f / (float)(BATCH * NROW));
        atomicAdd(out, tot);
    }
}

extern "C" void kernel_launch(void* const* d_in, const int* in_sizes, int n_in,
                              void* d_out, int out_size, void* d_ws, size_t ws_size,
                              hipStream_t stream) {
    const float* X   = (const float*)d_in[0];
    const int*   tok = (const int*)d_in[1];
    const float* E   = (const float*)d_in[2];
    float* out = (float*)d_out;

    // ws: [0,16MB) Ypk bf16 transposed, [16MB, +16KB) y2
    uint32_t* Ypk = (uint32_t*)d_ws;
    float*    y2  = (float*)((char*)d_ws + (size_t)BATCH * KC * LTOK * 16);

    hipMemsetAsync(out, 0, sizeof(float), stream);

    dim3 pgrid(LTOK, BATCH, 1);
    prep_y<<<pgrid, 256, 0, stream>>>(tok, E, Ypk, y2);

    cdist_min_mean_kernel<<<dim3(1024, 1, 1), 256, 0, stream>>>(
        X, (const short*)Ypk, y2, out);
}